// Round 9
// baseline (319.480 us; speedup 1.0000x reference)
//
#include <hip/hip_runtime.h>
#include <math.h>

#define N_NODES 20000
#define N_EDGES 320000
#define EMB 128
#define HID 512          // 4*EMB
#define PQ_STRIDE 1024   // P (512, bias-folded) + Q (512) per node
#define ROWS_PER_BLOCK 16
#define SC_CAP 2048      // LDS score cache per block
#define NCHUNK ((N_NODES + 1023) / 1024)   // 20

typedef float v2f __attribute__((ext_vector_type(2)));

#if defined(__has_builtin)
#if __has_builtin(__builtin_elementwise_fma)
#define V2FMA(a, b, c) __builtin_elementwise_fma((a), (b), (c))
#else
#define V2FMA(a, b, c) ((a) * (b) + (c))
#endif
#else
#define V2FMA(a, b, c) ((a) * (b) + (c))
#endif

// ---------------------------------------------------------------------------
__global__ void init_deg(int* __restrict__ deg, int* __restrict__ offs) {
    int i = blockIdx.x * 256 + threadIdx.x;
    if (i < N_NODES) deg[i] = 0;
    if (i == 0) offs[N_NODES] = N_EDGES;
}

__global__ void histogram_rows(const int* __restrict__ row, int* __restrict__ deg) {
    int e = blockIdx.x * 256 + threadIdx.x;
    if (e < N_EDGES) atomicAdd(&deg[row[e]], 1);
}

// ---------------------------------------------------------------------------
__device__ __forceinline__ int wave_incl_scan(int v, int lane) {
#pragma unroll
    for (int off = 1; off < 64; off <<= 1) {
        int t = __shfl_up(v, off, 64);
        if (lane >= off) v += t;
    }
    return v;
}

__global__ __launch_bounds__(1024) void scan_part(const int* __restrict__ deg,
                                                  int* __restrict__ part,
                                                  int* __restrict__ totals) {
    __shared__ int wsum[16];
    const int tid = threadIdx.x, lane = tid & 63, w = tid >> 6;
    const int i = blockIdx.x * 1024 + tid;
    int v = (i < N_NODES) ? deg[i] : 0;
    int incl = wave_incl_scan(v, lane);
    if (lane == 63) wsum[w] = incl;
    __syncthreads();
    if (w == 0) {
        int x = (lane < 16) ? wsum[lane] : 0;
        int xs = wave_incl_scan(x, lane);
        if (lane < 16) wsum[lane] = xs - x;
        if (lane == 15) totals[blockIdx.x] = xs;
    }
    __syncthreads();
    if (i < N_NODES) part[i] = wsum[w] + incl - v;
}

__global__ void scan_carry(const int* __restrict__ totals, int* __restrict__ carry) {
    const int lane = threadIdx.x;   // one wave
    int v = (lane < NCHUNK) ? totals[lane] : 0;
    int incl = wave_incl_scan(v, lane);
    if (lane < NCHUNK) carry[lane] = incl - v;
}

__global__ __launch_bounds__(1024) void scan_apply(const int* __restrict__ part,
                                                   const int* __restrict__ carry,
                                                   int* __restrict__ cursor,
                                                   int* __restrict__ offs) {
    const int i = blockIdx.x * 1024 + threadIdx.x;
    if (i < N_NODES) {
        int o = part[i] + carry[blockIdx.x];
        cursor[i] = o;
        offs[i] = o;
    }
}

// ---------------------------------------------------------------------------
// scatter: ONE int2 {e, row<<16|col} per edge (lossless: row,col < 32768)
// ---------------------------------------------------------------------------
__global__ void scatter_edges(const int* __restrict__ row, const int* __restrict__ col,
                              int* __restrict__ cursor, int2* __restrict__ rc2) {
    int e = blockIdx.x * 256 + threadIdx.x;
    if (e >= N_EDGES) return;
    int r = row[e];
    int pos = atomicAdd(&cursor[r], 1);
    rc2[pos] = make_int2(e, (r << 16) | col[e]);
}

// ---------------------------------------------------------------------------
// GEMM (unchanged from round 8): 128x128 tile, BK=8, 256 threads, 8x8 micro
// (pk-fma), LDS double-buffer.
// ---------------------------------------------------------------------------
#define TM 128
#define TN 128
#define BK 8
#define NTILES (EMB / BK)   // 16

__global__ __launch_bounds__(256) void gemm_pq(
    const float* __restrict__ h, const float* __restrict__ W1,
    const float* __restrict__ b1, float* __restrict__ PQ)
{
    __shared__ float As[2][BK][TM + 4];
    __shared__ float Bs[2][BK][TN];

    const int tid = threadIdx.x;
    const int nt  = blockIdx.x;
    const int mt  = blockIdx.y;
    const int m_base = mt * TM;

    const int a_m = tid >> 1;
    const int a_k = (tid & 1) << 2;
    const int  row_a = m_base + a_m;
    const bool a_ok  = row_a < N_NODES;
    const float* __restrict__ hrow = h + (size_t)row_a * EMB + a_k;

    const int b_k = tid >> 5;
    const int b_n = (tid & 31) << 2;
    const int w_row_off = (nt < 4) ? 0 : 128;
    const int w_col     = (nt & 3) * TN + b_n;
    const float* __restrict__ wrow = W1 + (size_t)(w_row_off + b_k) * HID + w_col;

    const int ty = tid >> 4, tx = tid & 15;
    const int cm = ty << 2, cn = tx << 2;

    v2f acc[8][4] = {};

    float4 pa, pb;
    pa = make_float4(0.f, 0.f, 0.f, 0.f);
    if (a_ok) pa = *(const float4*)(hrow);
    pb = *(const float4*)(wrow);
    As[0][a_k + 0][a_m] = pa.x;
    As[0][a_k + 1][a_m] = pa.y;
    As[0][a_k + 2][a_m] = pa.z;
    As[0][a_k + 3][a_m] = pa.w;
    *(float4*)&Bs[0][b_k][b_n] = pb;
    __syncthreads();

    for (int t = 0; t < NTILES; ++t) {
        const int cur = t & 1;
        if (t + 1 < NTILES) {
            const int k0 = (t + 1) * BK;
            pa = make_float4(0.f, 0.f, 0.f, 0.f);
            if (a_ok) pa = *(const float4*)(hrow + k0);
            pb = *(const float4*)(wrow + (size_t)k0 * HID);
        }

#pragma unroll
        for (int kk = 0; kk < BK; ++kk) {
            float a[8];
            *(float4*)&a[0] = *(const float4*)&As[cur][kk][cm];
            *(float4*)&a[4] = *(const float4*)&As[cur][kk][cm + 64];
            float4 b0 = *(const float4*)&Bs[cur][kk][cn];
            float4 b1v = *(const float4*)&Bs[cur][kk][cn + 64];
            v2f bp[4] = {(v2f){b0.x, b0.y}, (v2f){b0.z, b0.w},
                         (v2f){b1v.x, b1v.y}, (v2f){b1v.z, b1v.w}};
#pragma unroll
            for (int i = 0; i < 8; ++i) {
                v2f ai = (v2f){a[i], a[i]};
#pragma unroll
                for (int j = 0; j < 4; ++j)
                    acc[i][j] = V2FMA(ai, bp[j], acc[i][j]);
            }
        }

        if (t + 1 < NTILES) {
            const int nxt = 1 - cur;
            As[nxt][a_k + 0][a_m] = pa.x;
            As[nxt][a_k + 1][a_m] = pa.y;
            As[nxt][a_k + 2][a_m] = pa.z;
            As[nxt][a_k + 3][a_m] = pa.w;
            *(float4*)&Bs[nxt][b_k][b_n] = pb;
            __syncthreads();
        }
    }

    const int col_base = nt * TN;
    v2f bias[4] = {{0.f,0.f},{0.f,0.f},{0.f,0.f},{0.f,0.f}};
    if (nt < 4) {
        float4 bv0 = *(const float4*)(b1 + col_base + cn);
        float4 bv1 = *(const float4*)(b1 + col_base + cn + 64);
        bias[0] = (v2f){bv0.x, bv0.y};
        bias[1] = (v2f){bv0.z, bv0.w};
        bias[2] = (v2f){bv1.x, bv1.y};
        bias[3] = (v2f){bv1.z, bv1.w};
    }

#pragma unroll
    for (int i = 0; i < 8; ++i) {
        const int r = m_base + cm + (i < 4 ? i : 64 + i - 4);
        if (r < N_NODES) {
            float* dst = PQ + (size_t)r * PQ_STRIDE + col_base;
            v2f c0 = acc[i][0] + bias[0], c1 = acc[i][1] + bias[1];
            v2f c2 = acc[i][2] + bias[2], c3 = acc[i][3] + bias[3];
            *(float4*)(dst + cn)      = make_float4(c0.x, c0.y, c1.x, c1.y);
            *(float4*)(dst + cn + 64) = make_float4(c2.x, c2.y, c3.x, c3.y);
        }
    }
}

// ---------------------------------------------------------------------------
// Fused edge phase: SAME 1250 blocks / RPB=16 (identical traffic & locality)
// but 512 threads = 8 waves/block -> ~2x waves in flight (occupancy was
// grid-limited at 47%). Clean occupancy-vs-bandwidth experiment.
// ---------------------------------------------------------------------------
__global__ __launch_bounds__(512) void fused_edge(
    const float* __restrict__ PQ,
    const float* __restrict__ W2, const float* __restrict__ b2,
    const int2* __restrict__ rc2, const int* __restrict__ offs,
    const float* __restrict__ u, const int* __restrict__ edge_mask,
    const int* __restrict__ hierarchy,
    float* __restrict__ scores, float* __restrict__ out_y,
    float* __restrict__ out_mask, float* __restrict__ out_causal,
    float* __restrict__ out_spu)
{
    __shared__ float sc_lds[SC_CAP];

    const int r0 = blockIdx.x * ROWS_PER_BLOCK;
    const int r1 = (r0 + ROWS_PER_BLOCK < N_NODES) ? r0 + ROWS_PER_BLOCK : N_NODES;
    const int e0 = offs[r0];
    const int e1 = offs[r1];
    const int tid = threadIdx.x, lane = tid & 63, w = tid >> 6;   // w: 0..7
    const int j0 = lane << 2;

    const float4 w0 = *(const float4*)(W2 + j0);
    const float4 w1 = *(const float4*)(W2 + 256 + j0);
    const float bias2 = b2[0];

    // ---- phase 1: scores, two edges per wave-iteration, 8 waves ----
    for (int i0 = e0 + (w << 1); i0 < e1; i0 += 16) {
        const int  iA   = i0;
        const bool hasB = (i0 + 1) < e1;
        const int  iB   = hasB ? i0 + 1 : i0;

        const int2 eA = rc2[iA];
        const int2 eB = rc2[iB];
        const int rA = ((unsigned)eA.y) >> 16, cA = eA.y & 0xFFFF;
        const int rB = ((unsigned)eB.y) >> 16, cB = eB.y & 0xFFFF;
        const float* __restrict__ pA = PQ + (size_t)rA * PQ_STRIDE;
        const float* __restrict__ qA = PQ + (size_t)cA * PQ_STRIDE + HID;
        const float* __restrict__ pB = PQ + (size_t)rB * PQ_STRIDE;
        const float* __restrict__ qB = PQ + (size_t)cB * PQ_STRIDE + HID;

        float4 pA0 = *(const float4*)(pA + j0);
        float4 pA1 = *(const float4*)(pA + 256 + j0);
        float4 qA0 = *(const float4*)(qA + j0);
        float4 qA1 = *(const float4*)(qA + 256 + j0);
        float4 pB0 = *(const float4*)(pB + j0);
        float4 pB1 = *(const float4*)(pB + 256 + j0);
        float4 qB0 = *(const float4*)(qB + j0);
        float4 qB1 = *(const float4*)(qB + 256 + j0);

        float sA = 0.0f, sB = 0.0f;
        sA = fmaf(fmaxf(pA0.x + qA0.x, 0.0f), w0.x, sA);
        sA = fmaf(fmaxf(pA0.y + qA0.y, 0.0f), w0.y, sA);
        sA = fmaf(fmaxf(pA0.z + qA0.z, 0.0f), w0.z, sA);
        sA = fmaf(fmaxf(pA0.w + qA0.w, 0.0f), w0.w, sA);
        sA = fmaf(fmaxf(pA1.x + qA1.x, 0.0f), w1.x, sA);
        sA = fmaf(fmaxf(pA1.y + qA1.y, 0.0f), w1.y, sA);
        sA = fmaf(fmaxf(pA1.z + qA1.z, 0.0f), w1.z, sA);
        sA = fmaf(fmaxf(pA1.w + qA1.w, 0.0f), w1.w, sA);
        sB = fmaf(fmaxf(pB0.x + qB0.x, 0.0f), w0.x, sB);
        sB = fmaf(fmaxf(pB0.y + qB0.y, 0.0f), w0.y, sB);
        sB = fmaf(fmaxf(pB0.z + qB0.z, 0.0f), w0.z, sB);
        sB = fmaf(fmaxf(pB0.w + qB0.w, 0.0f), w0.w, sB);
        sB = fmaf(fmaxf(pB1.x + qB1.x, 0.0f), w1.x, sB);
        sB = fmaf(fmaxf(pB1.y + qB1.y, 0.0f), w1.y, sB);
        sB = fmaf(fmaxf(pB1.z + qB1.z, 0.0f), w1.z, sB);
        sB = fmaf(fmaxf(pB1.w + qB1.w, 0.0f), w1.w, sB);

#pragma unroll
        for (int off = 32; off > 0; off >>= 1) {
            sA += __shfl_down(sA, off, 64);
            sB += __shfl_down(sB, off, 64);
        }

        if (lane == 0) {
            float scA = sA + bias2;
            scores[eA.x] = scA;
            int liA = iA - e0;
            if (liA < SC_CAP) sc_lds[liA] = scA;
            if (hasB) {
                float scB = sB + bias2;
                scores[eB.x] = scB;
                int liB = iB - e0;
                if (liB < SC_CAP) sc_lds[liB] = scB;
            }
        }
    }
    __syncthreads();

    // ---- phase 2: wave per row (8 waves, 16 rows -> 2 rows/wave) ----
    const int hv = hierarchy[0];
    for (int r = r0 + w; r < r1; r += 8) {
        const int es = offs[r], ee = offs[r + 1];
        const int d = ee - es;
        if (d == 0) continue;

        float m = -INFINITY;
        for (int j = lane; j < d; j += 64) {
            int li = es - e0 + j;
            float s = (li < SC_CAP) ? sc_lds[li] : scores[rc2[es + j].x];
            m = fmaxf(m, s);
        }
#pragma unroll
        for (int off = 32; off > 0; off >>= 1)
            m = fmaxf(m, __shfl_down(m, off, 64));
        m = __shfl(m, 0, 64);

        float ssum = 0.0f;
        for (int j = lane; j < d; j += 64) {
            int li = es - e0 + j;
            float s = (li < SC_CAP) ? sc_lds[li] : scores[rc2[es + j].x];
            ssum += expf(s - m);
        }
#pragma unroll
        for (int off = 32; off > 0; off >>= 1)
            ssum += __shfl_down(ssum, off, 64);
        ssum = __shfl(ssum, 0, 64);

        for (int j = lane; j < d; j += 64) {
            int li = es - e0 + j;
            float s = (li < SC_CAP) ? sc_lds[li] : scores[rc2[es + j].x];
            float p = expf(s - m) / ssum;
            float logits = logf(p) - log1pf(-p);   // +inf when p==1 (d==1)
            int oe = rc2[es + j].x;
            float uu = u[oe];
            float L = logf(uu) - log1pf(-uu);
            float y = 1.0f / (1.0f + expf(-(logits + L)));
            bool hard = y > 0.5f;                  // ST forward value == y_hard
            int mm = hard ? (hv + 1) : edge_mask[oe];
            out_y[oe]      = hard ? 1.0f : 0.0f;
            out_mask[oe]   = (float)mm;
            out_causal[oe] = (mm > 0)   ?  s : 0.0f;
            out_spu[oe]    = (mm == -1) ? -s : 0.0f;
        }
    }
}

// ---------------------------------------------------------------------------
extern "C" void kernel_launch(void* const* d_in, const int* in_sizes, int n_in,
                              void* d_out, int out_size, void* d_ws, size_t ws_size,
                              hipStream_t stream) {
    const float* h_ptr = (const float*)d_in[0];
    const float* W1    = (const float*)d_in[1];
    const float* b1    = (const float*)d_in[2];
    const float* W2    = (const float*)d_in[3];
    const float* b2    = (const float*)d_in[4];
    const float* u     = (const float*)d_in[5];
    const int*   row   = (const int*)d_in[6];
    const int*   col   = (const int*)d_in[7];
    const int*   emask = (const int*)d_in[8];
    const int*   hier  = (const int*)d_in[9];

    float* out        = (float*)d_out;
    float* scores     = out;                        // [E]
    float* out_y      = out + (size_t)N_EDGES;      // [E]
    float* out_mask   = out + 2 * (size_t)N_EDGES;  // [E]
    float* out_causal = out + 3 * (size_t)N_EDGES;  // [E]
    float* out_spu    = out + 4 * (size_t)N_EDGES;  // [E]

    // workspace (4B units), PQ first (16B align), rc2 second (8B align):
    float* PQ     = (float*)d_ws;
    int2*  rc2    = (int2*)(PQ + (size_t)N_NODES * PQ_STRIDE);   // [E] int2
    int*   deg    = (int*)(rc2 + N_EDGES);
    int*   cursor = deg + N_NODES;
    int*   offs   = cursor + N_NODES;               // [N_NODES+1]
    int*   part   = offs + N_NODES + 1;
    int*   totals = part + N_NODES;                 // [NCHUNK]
    int*   carry  = totals + NCHUNK;                // [NCHUNK]

    hipLaunchKernelGGL(init_deg, dim3((N_NODES + 255) / 256), dim3(256), 0, stream,
                       deg, offs);
    hipLaunchKernelGGL(histogram_rows, dim3((N_EDGES + 255) / 256), dim3(256), 0, stream,
                       row, deg);
    hipLaunchKernelGGL(scan_part, dim3(NCHUNK), dim3(1024), 0, stream, deg, part, totals);
    hipLaunchKernelGGL(scan_carry, dim3(1), dim3(64), 0, stream, totals, carry);
    hipLaunchKernelGGL(scan_apply, dim3(NCHUNK), dim3(1024), 0, stream,
                       part, carry, cursor, offs);
    hipLaunchKernelGGL(scatter_edges, dim3((N_EDGES + 255) / 256), dim3(256), 0, stream,
                       row, col, cursor, rc2);

    dim3 ggrid(PQ_STRIDE / TN, (N_NODES + TM - 1) / TM);  // 8 x 157
    hipLaunchKernelGGL(gemm_pq, ggrid, dim3(256), 0, stream, h_ptr, W1, b1, PQ);

    hipLaunchKernelGGL(fused_edge, dim3((N_NODES + ROWS_PER_BLOCK - 1) / ROWS_PER_BLOCK),
                       dim3(512), 0, stream,
                       PQ, W2, b2, rc2, offs, u, emask, hier,
                       scores, out_y, out_mask, out_causal, out_spu);
}

// Round 10
// 286.473 us; speedup vs baseline: 1.1152x; 1.1152x over previous
//
#include <hip/hip_runtime.h>
#include <math.h>

#define N_NODES 20000
#define N_EDGES 320000
#define EMB 128
#define HID 512          // 4*EMB
#define ROWS_PER_BLOCK 16
#define SC_CAP 2048      // LDS score cache per block
#define NCHUNK ((N_NODES + 1023) / 1024)   // 20

typedef float v2f __attribute__((ext_vector_type(2)));

#if defined(__has_builtin)
#if __has_builtin(__builtin_elementwise_fma)
#define V2FMA(a, b, c) __builtin_elementwise_fma((a), (b), (c))
#else
#define V2FMA(a, b, c) ((a) * (b) + (c))
#endif
#else
#define V2FMA(a, b, c) ((a) * (b) + (c))
#endif

// ---------------------------------------------------------------------------
__global__ void init_deg(int* __restrict__ deg, int* __restrict__ offs) {
    int i = blockIdx.x * 256 + threadIdx.x;
    if (i < N_NODES) deg[i] = 0;
    if (i == 0) offs[N_NODES] = N_EDGES;
}

// ---------------------------------------------------------------------------
// K2: heterogeneous blocks — [0,GEMM_BLOCKS) = GEMM, rest = row histogram.
// The two paths touch disjoint memory; no synchronization needed (unlike the
// failed round-7 ticket variant). Histogram (~10us of block-time) rides on
// CUs the gemm leaves idle.
//
// GEMM: P[n][0:512] = h@W1[0:128,:] + b1 ; Q[n][0:512] = h@W1[128:256,:]
// (separate arrays: Q-gathers in fused_edge then randomize over 41 MB, not
// 82 MB -> better L2/L3 residency). 128x128 tile, BK=8, 256 thr, 8x8 micro
// (pk-fma), LDS double-buffer.
// ---------------------------------------------------------------------------
#define TM 128
#define TN 128
#define BK 8
#define NTILES (EMB / BK)                   // 16
#define GEMM_MT ((N_NODES + TM - 1) / TM)   // 157
#define GEMM_BLOCKS (8 * GEMM_MT)           // 1256
#define HIST_BLOCKS ((N_EDGES + 255) / 256) // 1250

__global__ __launch_bounds__(256) void gemm_hist(
    const float* __restrict__ h, const float* __restrict__ W1,
    const float* __restrict__ b1, float* __restrict__ P, float* __restrict__ Q,
    const int* __restrict__ row, int* __restrict__ deg)
{
    const int bid = blockIdx.x;
    const int tid = threadIdx.x;

    if (bid >= GEMM_BLOCKS) {
        // ---- histogram path ----
        const int e = (bid - GEMM_BLOCKS) * 256 + tid;
        if (e < N_EDGES) atomicAdd(&deg[row[e]], 1);
        return;
    }

    // ---- gemm path ----
    __shared__ float As[2][BK][TM + 4];
    __shared__ float Bs[2][BK][TN];

    const int nt = bid & 7;        // 0..7 (1256 = 8*157 exactly)
    const int mt = bid >> 3;       // 0..156
    const int m_base = mt * TM;

    const int a_m = tid >> 1;
    const int a_k = (tid & 1) << 2;
    const int  row_a = m_base + a_m;
    const bool a_ok  = row_a < N_NODES;
    const float* __restrict__ hrow = h + (size_t)row_a * EMB + a_k;

    const int b_k = tid >> 5;
    const int b_n = (tid & 31) << 2;
    const int w_row_off = (nt < 4) ? 0 : 128;
    const int w_col     = (nt & 3) * TN + b_n;
    const float* __restrict__ wrow = W1 + (size_t)(w_row_off + b_k) * HID + w_col;

    const int ty = tid >> 4, tx = tid & 15;
    const int cm = ty << 2, cn = tx << 2;

    v2f acc[8][4] = {};

    float4 pa, pb;
    pa = make_float4(0.f, 0.f, 0.f, 0.f);
    if (a_ok) pa = *(const float4*)(hrow);
    pb = *(const float4*)(wrow);
    As[0][a_k + 0][a_m] = pa.x;
    As[0][a_k + 1][a_m] = pa.y;
    As[0][a_k + 2][a_m] = pa.z;
    As[0][a_k + 3][a_m] = pa.w;
    *(float4*)&Bs[0][b_k][b_n] = pb;
    __syncthreads();

    for (int t = 0; t < NTILES; ++t) {
        const int cur = t & 1;
        if (t + 1 < NTILES) {
            const int k0 = (t + 1) * BK;
            pa = make_float4(0.f, 0.f, 0.f, 0.f);
            if (a_ok) pa = *(const float4*)(hrow + k0);
            pb = *(const float4*)(wrow + (size_t)k0 * HID);
        }

#pragma unroll
        for (int kk = 0; kk < BK; ++kk) {
            float a[8];
            *(float4*)&a[0] = *(const float4*)&As[cur][kk][cm];
            *(float4*)&a[4] = *(const float4*)&As[cur][kk][cm + 64];
            float4 b0 = *(const float4*)&Bs[cur][kk][cn];
            float4 b1v = *(const float4*)&Bs[cur][kk][cn + 64];
            v2f bp[4] = {(v2f){b0.x, b0.y}, (v2f){b0.z, b0.w},
                         (v2f){b1v.x, b1v.y}, (v2f){b1v.z, b1v.w}};
#pragma unroll
            for (int i = 0; i < 8; ++i) {
                v2f ai = (v2f){a[i], a[i]};
#pragma unroll
                for (int j = 0; j < 4; ++j)
                    acc[i][j] = V2FMA(ai, bp[j], acc[i][j]);
            }
        }

        if (t + 1 < NTILES) {
            const int nxt = 1 - cur;
            As[nxt][a_k + 0][a_m] = pa.x;
            As[nxt][a_k + 1][a_m] = pa.y;
            As[nxt][a_k + 2][a_m] = pa.z;
            As[nxt][a_k + 3][a_m] = pa.w;
            *(float4*)&Bs[nxt][b_k][b_n] = pb;
            __syncthreads();
        }
    }

    const bool  isP = (nt < 4);
    const int   col_base = (nt & 3) * TN;
    float* __restrict__ dstbase = isP ? P : Q;

    v2f bias[4] = {{0.f,0.f},{0.f,0.f},{0.f,0.f},{0.f,0.f}};
    if (isP) {  // bias fold: P half only
        float4 bv0 = *(const float4*)(b1 + col_base + cn);
        float4 bv1 = *(const float4*)(b1 + col_base + cn + 64);
        bias[0] = (v2f){bv0.x, bv0.y};
        bias[1] = (v2f){bv0.z, bv0.w};
        bias[2] = (v2f){bv1.x, bv1.y};
        bias[3] = (v2f){bv1.z, bv1.w};
    }

#pragma unroll
    for (int i = 0; i < 8; ++i) {
        const int r = m_base + cm + (i < 4 ? i : 64 + i - 4);
        if (r < N_NODES) {
            float* dst = dstbase + (size_t)r * HID + col_base;
            v2f c0 = acc[i][0] + bias[0], c1 = acc[i][1] + bias[1];
            v2f c2 = acc[i][2] + bias[2], c3 = acc[i][3] + bias[3];
            *(float4*)(dst + cn)      = make_float4(c0.x, c0.y, c1.x, c1.y);
            *(float4*)(dst + cn + 64) = make_float4(c2.x, c2.y, c3.x, c3.y);
        }
    }
}

// ---------------------------------------------------------------------------
__device__ __forceinline__ int wave_incl_scan(int v, int lane) {
#pragma unroll
    for (int off = 1; off < 64; off <<= 1) {
        int t = __shfl_up(v, off, 64);
        if (lane >= off) v += t;
    }
    return v;
}

__global__ __launch_bounds__(1024) void scan_part(const int* __restrict__ deg,
                                                  int* __restrict__ part,
                                                  int* __restrict__ totals) {
    __shared__ int wsum[16];
    const int tid = threadIdx.x, lane = tid & 63, w = tid >> 6;
    const int i = blockIdx.x * 1024 + tid;
    int v = (i < N_NODES) ? deg[i] : 0;
    int incl = wave_incl_scan(v, lane);
    if (lane == 63) wsum[w] = incl;
    __syncthreads();
    if (w == 0) {
        int x = (lane < 16) ? wsum[lane] : 0;
        int xs = wave_incl_scan(x, lane);
        if (lane < 16) wsum[lane] = xs - x;
        if (lane == 15) totals[blockIdx.x] = xs;
    }
    __syncthreads();
    if (i < N_NODES) part[i] = wsum[w] + incl - v;
}

// scan_carry folded in: every block redundantly scans the 20 chunk totals.
__global__ __launch_bounds__(1024) void scan_apply(const int* __restrict__ part,
                                                   const int* __restrict__ totals,
                                                   int* __restrict__ cursor,
                                                   int* __restrict__ offs) {
    __shared__ int carry_s;
    const int tid = threadIdx.x;
    if (tid < 64) {
        int v = (tid < NCHUNK) ? totals[tid] : 0;
        int incl = wave_incl_scan(v, tid);
        if (tid == (int)blockIdx.x) carry_s = incl - v;   // exclusive carry
    }
    __syncthreads();
    const int i = blockIdx.x * 1024 + tid;
    if (i < N_NODES) {
        int o = part[i] + carry_s;
        cursor[i] = o;
        offs[i] = o;
    }
}

// ---------------------------------------------------------------------------
// scatter: ONE int2 {e, row<<16|col} per edge (lossless: row,col < 32768)
// ---------------------------------------------------------------------------
__global__ void scatter_edges(const int* __restrict__ row, const int* __restrict__ col,
                              int* __restrict__ cursor, int2* __restrict__ rc2) {
    int e = blockIdx.x * 256 + threadIdx.x;
    if (e >= N_EDGES) return;
    int r = row[e];
    int pos = atomicAdd(&cursor[r], 1);
    rc2[pos] = make_int2(e, (r << 16) | col[e]);
}

// ---------------------------------------------------------------------------
// Fused edge phase — round-8 champion (256 thr, RPB=16, x2 unroll; occupancy
// experiments r6/r9 both showed more waves = more thrash = slower).
// P/Q now separate 41 MB arrays.
// ---------------------------------------------------------------------------
__global__ __launch_bounds__(256) void fused_edge(
    const float* __restrict__ P, const float* __restrict__ Q,
    const float* __restrict__ W2, const float* __restrict__ b2,
    const int2* __restrict__ rc2, const int* __restrict__ offs,
    const float* __restrict__ u, const int* __restrict__ edge_mask,
    const int* __restrict__ hierarchy,
    float* __restrict__ scores, float* __restrict__ out_y,
    float* __restrict__ out_mask, float* __restrict__ out_causal,
    float* __restrict__ out_spu)
{
    __shared__ float sc_lds[SC_CAP];

    const int r0 = blockIdx.x * ROWS_PER_BLOCK;
    const int r1 = (r0 + ROWS_PER_BLOCK < N_NODES) ? r0 + ROWS_PER_BLOCK : N_NODES;
    const int e0 = offs[r0];
    const int e1 = offs[r1];
    const int tid = threadIdx.x, lane = tid & 63, w = tid >> 6;
    const int j0 = lane << 2;

    const float4 w0 = *(const float4*)(W2 + j0);
    const float4 w1 = *(const float4*)(W2 + 256 + j0);
    const float bias2 = b2[0];

    // ---- phase 1: scores, two edges per wave-iteration ----
    for (int i0 = e0 + (w << 1); i0 < e1; i0 += 8) {
        const int  iA   = i0;
        const bool hasB = (i0 + 1) < e1;
        const int  iB   = hasB ? i0 + 1 : i0;

        const int2 eA = rc2[iA];
        const int2 eB = rc2[iB];
        const int rA = ((unsigned)eA.y) >> 16, cA = eA.y & 0xFFFF;
        const int rB = ((unsigned)eB.y) >> 16, cB = eB.y & 0xFFFF;
        const float* __restrict__ pA = P + (size_t)rA * HID;
        const float* __restrict__ qA = Q + (size_t)cA * HID;
        const float* __restrict__ pB = P + (size_t)rB * HID;
        const float* __restrict__ qB = Q + (size_t)cB * HID;

        float4 pA0 = *(const float4*)(pA + j0);
        float4 pA1 = *(const float4*)(pA + 256 + j0);
        float4 qA0 = *(const float4*)(qA + j0);
        float4 qA1 = *(const float4*)(qA + 256 + j0);
        float4 pB0 = *(const float4*)(pB + j0);
        float4 pB1 = *(const float4*)(pB + 256 + j0);
        float4 qB0 = *(const float4*)(qB + j0);
        float4 qB1 = *(const float4*)(qB + 256 + j0);

        float sA = 0.0f, sB = 0.0f;
        sA = fmaf(fmaxf(pA0.x + qA0.x, 0.0f), w0.x, sA);
        sA = fmaf(fmaxf(pA0.y + qA0.y, 0.0f), w0.y, sA);
        sA = fmaf(fmaxf(pA0.z + qA0.z, 0.0f), w0.z, sA);
        sA = fmaf(fmaxf(pA0.w + qA0.w, 0.0f), w0.w, sA);
        sA = fmaf(fmaxf(pA1.x + qA1.x, 0.0f), w1.x, sA);
        sA = fmaf(fmaxf(pA1.y + qA1.y, 0.0f), w1.y, sA);
        sA = fmaf(fmaxf(pA1.z + qA1.z, 0.0f), w1.z, sA);
        sA = fmaf(fmaxf(pA1.w + qA1.w, 0.0f), w1.w, sA);
        sB = fmaf(fmaxf(pB0.x + qB0.x, 0.0f), w0.x, sB);
        sB = fmaf(fmaxf(pB0.y + qB0.y, 0.0f), w0.y, sB);
        sB = fmaf(fmaxf(pB0.z + qB0.z, 0.0f), w0.z, sB);
        sB = fmaf(fmaxf(pB0.w + qB0.w, 0.0f), w0.w, sB);
        sB = fmaf(fmaxf(pB1.x + qB1.x, 0.0f), w1.x, sB);
        sB = fmaf(fmaxf(pB1.y + qB1.y, 0.0f), w1.y, sB);
        sB = fmaf(fmaxf(pB1.z + qB1.z, 0.0f), w1.z, sB);
        sB = fmaf(fmaxf(pB1.w + qB1.w, 0.0f), w1.w, sB);

#pragma unroll
        for (int off = 32; off > 0; off >>= 1) {
            sA += __shfl_down(sA, off, 64);
            sB += __shfl_down(sB, off, 64);
        }

        if (lane == 0) {
            float scA = sA + bias2;
            scores[eA.x] = scA;
            int liA = iA - e0;
            if (liA < SC_CAP) sc_lds[liA] = scA;
            if (hasB) {
                float scB = sB + bias2;
                scores[eB.x] = scB;
                int liB = iB - e0;
                if (liB < SC_CAP) sc_lds[liB] = scB;
            }
        }
    }
    __syncthreads();

    // ---- phase 2: wave per row ----
    const int hv = hierarchy[0];
    for (int r = r0 + w; r < r1; r += 4) {
        const int es = offs[r], ee = offs[r + 1];
        const int d = ee - es;
        if (d == 0) continue;

        float m = -INFINITY;
        for (int j = lane; j < d; j += 64) {
            int li = es - e0 + j;
            float s = (li < SC_CAP) ? sc_lds[li] : scores[rc2[es + j].x];
            m = fmaxf(m, s);
        }
#pragma unroll
        for (int off = 32; off > 0; off >>= 1)
            m = fmaxf(m, __shfl_down(m, off, 64));
        m = __shfl(m, 0, 64);

        float ssum = 0.0f;
        for (int j = lane; j < d; j += 64) {
            int li = es - e0 + j;
            float s = (li < SC_CAP) ? sc_lds[li] : scores[rc2[es + j].x];
            ssum += expf(s - m);
        }
#pragma unroll
        for (int off = 32; off > 0; off >>= 1)
            ssum += __shfl_down(ssum, off, 64);
        ssum = __shfl(ssum, 0, 64);

        for (int j = lane; j < d; j += 64) {
            int li = es - e0 + j;
            float s = (li < SC_CAP) ? sc_lds[li] : scores[rc2[es + j].x];
            float p = expf(s - m) / ssum;
            float logits = logf(p) - log1pf(-p);   // +inf when p==1 (d==1)
            int oe = rc2[es + j].x;
            float uu = u[oe];
            float L = logf(uu) - log1pf(-uu);
            float y = 1.0f / (1.0f + expf(-(logits + L)));
            bool hard = y > 0.5f;                  // ST forward value == y_hard
            int mm = hard ? (hv + 1) : edge_mask[oe];
            out_y[oe]      = hard ? 1.0f : 0.0f;
            out_mask[oe]   = (float)mm;
            out_causal[oe] = (mm > 0)   ?  s : 0.0f;
            out_spu[oe]    = (mm == -1) ? -s : 0.0f;
        }
    }
}

// ---------------------------------------------------------------------------
extern "C" void kernel_launch(void* const* d_in, const int* in_sizes, int n_in,
                              void* d_out, int out_size, void* d_ws, size_t ws_size,
                              hipStream_t stream) {
    const float* h_ptr = (const float*)d_in[0];
    const float* W1    = (const float*)d_in[1];
    const float* b1    = (const float*)d_in[2];
    const float* W2    = (const float*)d_in[3];
    const float* b2    = (const float*)d_in[4];
    const float* u     = (const float*)d_in[5];
    const int*   row   = (const int*)d_in[6];
    const int*   col   = (const int*)d_in[7];
    const int*   emask = (const int*)d_in[8];
    const int*   hier  = (const int*)d_in[9];

    float* out        = (float*)d_out;
    float* scores     = out;                        // [E]
    float* out_y      = out + (size_t)N_EDGES;      // [E]
    float* out_mask   = out + 2 * (size_t)N_EDGES;  // [E]
    float* out_causal = out + 3 * (size_t)N_EDGES;  // [E]
    float* out_spu    = out + 4 * (size_t)N_EDGES;  // [E]

    // workspace (4B units): P, Q first (16B align), rc2 (8B align), then ints
    float* P      = (float*)d_ws;
    float* Qm     = P + (size_t)N_NODES * HID;
    int2*  rc2    = (int2*)(Qm + (size_t)N_NODES * HID);   // [E] int2
    int*   deg    = (int*)(rc2 + N_EDGES);
    int*   cursor = deg + N_NODES;
    int*   offs   = cursor + N_NODES;               // [N_NODES+1]
    int*   part   = offs + N_NODES + 1;
    int*   totals = part + N_NODES;                 // [NCHUNK]

    hipLaunchKernelGGL(init_deg, dim3((N_NODES + 255) / 256), dim3(256), 0, stream,
                       deg, offs);

    hipLaunchKernelGGL(gemm_hist, dim3(GEMM_BLOCKS + HIST_BLOCKS), dim3(256), 0, stream,
                       h_ptr, W1, b1, P, Qm, row, deg);

    hipLaunchKernelGGL(scan_part, dim3(NCHUNK), dim3(1024), 0, stream, deg, part, totals);
    hipLaunchKernelGGL(scan_apply, dim3(NCHUNK), dim3(1024), 0, stream,
                       part, totals, cursor, offs);
    hipLaunchKernelGGL(scatter_edges, dim3((N_EDGES + 255) / 256), dim3(256), 0, stream,
                       row, col, cursor, rc2);

    hipLaunchKernelGGL(fused_edge, dim3((N_NODES + ROWS_PER_BLOCK - 1) / ROWS_PER_BLOCK),
                       dim3(256), 0, stream,
                       P, Qm, W2, b2, rc2, offs, u, emask, hier,
                       scores, out_y, out_mask, out_causal, out_spu);
}